// Round 5
// baseline (1638.590 us; speedup 1.0000x reference)
//
#include <hip/hip_runtime.h>
#include <math.h>

#define NN 50000
#define NE 800000
#define NG 500
#define NCONV 13
#define WSTRIDE 304   // 289 weights per conv, padded
#define SCAN_B 196    // ceil(NN/256)
#define NBN 12        // convs 0..11 produce BN inputs for convs 1..12
#define BNP_REPS 64   // replication factor for bn partial atomics

// ---------------- CSR build ----------------

__global__ void zero_init_k(int* __restrict__ cursor, float* __restrict__ pooled,
                            float* __restrict__ bnpart) {
    int i = blockIdx.x * 256 + threadIdx.x;  // grid covers 98304
    if (i < NN) cursor[i] = 0;
    if (i < NG * 64) pooled[i] = 0.f;
    if (i < NBN * BNP_REPS * 128) bnpart[i] = 0.f;
}

__global__ void count_k(const int* __restrict__ dstp, int* __restrict__ cnt) {
    int e = blockIdx.x * 256 + threadIdx.x;
    if (e >= NE) return;
    atomicAdd(cnt + dstp[e], 1);
}

// phase A: per-block sums of counts (coalesced)
__global__ __launch_bounds__(256) void scan_blocksum_k(const int* __restrict__ cnt, int* __restrict__ bsum) {
    int i = blockIdx.x * 256 + threadIdx.x;
    int v = (i < NN) ? cnt[i] : 0;
    __shared__ int red[256];
    red[threadIdx.x] = v;
    __syncthreads();
    for (int off = 128; off > 0; off >>= 1) {
        if (threadIdx.x < off) red[threadIdx.x] += red[threadIdx.x + off];
        __syncthreads();
    }
    if (threadIdx.x == 0) bsum[blockIdx.x] = red[0];
}

// phase B: exclusive scan of the 196 block sums (single tiny block)
__global__ __launch_bounds__(256) void scan_bsum_k(int* __restrict__ bsum, int* __restrict__ row_start) {
    __shared__ int ss[256];
    int t = threadIdx.x;
    int v = (t < SCAN_B) ? bsum[t] : 0;
    ss[t] = v;
    __syncthreads();
    for (int off = 1; off < 256; off <<= 1) {
        int add = (t >= off) ? ss[t - off] : 0;
        __syncthreads();
        ss[t] += add;
        __syncthreads();
    }
    if (t < SCAN_B) bsum[t] = (t == 0) ? 0 : ss[t - 1];
    if (t == 0) row_start[NN] = NE;
}

// phase C: local block scan + block offset -> row_start and scatter cursor
__global__ __launch_bounds__(256) void scan_local_k(int* __restrict__ cnt_cursor, const int* __restrict__ bsum,
                                                    int* __restrict__ row_start) {
    __shared__ int ss[256];
    int i = blockIdx.x * 256 + threadIdx.x;
    int t = threadIdx.x;
    int v = (i < NN) ? cnt_cursor[i] : 0;
    ss[t] = v;
    __syncthreads();
    for (int off = 1; off < 256; off <<= 1) {
        int add = (t >= off) ? ss[t - off] : 0;
        __syncthreads();
        ss[t] += add;
        __syncthreads();
    }
    int excl = bsum[blockIdx.x] + ((t == 0) ? 0 : ss[t - 1]);
    if (i < NN) {
        row_start[i] = excl;
        cnt_cursor[i] = excl;  // becomes scatter cursor
    }
}

__global__ void scatter_k(const int* __restrict__ srcp, const int* __restrict__ dstp,
                          int* __restrict__ cursor, int* __restrict__ csr_src, int* __restrict__ csr_eid) {
    int e = blockIdx.x * 256 + threadIdx.x;
    if (e >= NE) return;
    int p = atomicAdd(cursor + dstp[e], 1);
    csr_src[p] = srcp[e];
    csr_eid[p] = e;
}

// ---------------- edge MLPs (all 13 convs, CSR order) ----------------

__global__ void pack_weights_k(const float* __restrict__ m1W1, const float* __restrict__ m1b1,
                               const float* __restrict__ m2W1, const float* __restrict__ m2b1,
                               const float* __restrict__ hm1W, const float* __restrict__ hm1b,
                               const float* __restrict__ hm2W, const float* __restrict__ hm2b,
                               float* __restrict__ wbuf) {
    int i = blockIdx.x * 256 + threadIdx.x;
    if (i >= NCONV * 289) return;
    int cc = i / 289, r = i % 289;
    float v;
    if (r < 256)      v = cc ? hm1W[(cc - 1) * 256 + r] : m1W1[r];
    else if (r < 272) v = cc ? hm1b[(cc - 1) * 16 + (r - 256)] : m1b1[r - 256];
    else if (r < 288) v = cc ? hm2W[(cc - 1) * 16 + (r - 272)] : m2W1[r - 272];
    else              v = cc ? hm2b[cc - 1] : m2b1[0];
    wbuf[cc * WSTRIDE + r] = v;
}

__global__ __launch_bounds__(256, 4) void edge_mlp_k(const float* __restrict__ attr, const int* __restrict__ eid_arr,
                                                     const float* __restrict__ wbuf, float* __restrict__ ew) {
    int k = blockIdx.x * 256 + threadIdx.x;
    if (k >= NE) return;
    int eid = eid_arr[k];
    const float4* a4 = (const float4*)(attr + (size_t)eid * 16);
    float4 A0 = a4[0], A1 = a4[1], A2 = a4[2], A3 = a4[3];
    float a[16] = {A0.x, A0.y, A0.z, A0.w, A1.x, A1.y, A1.z, A1.w,
                   A2.x, A2.y, A2.z, A2.w, A3.x, A3.y, A3.z, A3.w};
    for (int cc = 0; cc < NCONV; cc++) {
        const float* wb = wbuf + cc * WSTRIDE;  // uniform address -> s_load
        float hb[16];
        #pragma unroll
        for (int o = 0; o < 16; o++) hb[o] = wb[256 + o];
        #pragma unroll
        for (int i = 0; i < 16; i++) {
            float av = a[i];
            #pragma unroll
            for (int o = 0; o < 16; o++) hb[o] = fmaf(av, wb[i * 16 + o], hb[o]);
        }
        float z = wb[288];
        #pragma unroll
        for (int o = 0; o < 16; o++) {
            float hv = hb[o] > 0.f ? hb[o] : 0.f;
            z = fmaf(hv, wb[272 + o], z);
        }
        ew[(size_t)cc * NE + k] = 1.f / (1.f + __expf(-z));
    }
}

// deg = 1 + sum of incoming ew; dis = rsqrt(deg)  (deg >= 1 always)
__global__ void deg_dis_k(const int* __restrict__ row_start, const float* __restrict__ ew,
                          float* __restrict__ dis) {
    int n = blockIdx.x * 256 + threadIdx.x;
    int cc = blockIdx.y;
    if (n >= NN) return;
    int s0 = row_start[n], s1 = row_start[n + 1];
    const float* e = ew + (size_t)cc * NE;
    float s = 1.f;
    for (int k = s0; k < s1; k++) s += e[k];
    dis[cc * NN + n] = rsqrtf(s);
}

// ---------------- GEMM: H = bn_relu(X) @ W  (4 threads/row, 16 cols each) ----------------
// BN stats come from bnpart (BNP_REPS x 128 atomic partials written by the previous
// aggregate's epilogue); reduced redundantly in every block's prologue (32 KB L2-hit).

template <bool BN>
__global__ __launch_bounds__(256) void gemm_k(const float* __restrict__ X, const float* __restrict__ Wg,
                                              const float* __restrict__ bnpart, float* __restrict__ H) {
    __shared__ float bsum[128];
    __shared__ float mus[64];
    __shared__ float invs[64];
    int t = threadIdx.x;
    if (BN) {
        if (t < 128) {
            float s = 0.f;
            for (int rp = 0; rp < BNP_REPS; rp++) s += bnpart[rp * 128 + t];
            bsum[t] = s;
        }
        __syncthreads();
        if (t < 64) {
            float mu = bsum[t] * (1.f / NN);
            float var = bsum[64 + t] * (1.f / NN) - mu * mu;
            var = var < 0.f ? 0.f : var;
            mus[t] = mu;
            invs[t] = rsqrtf(var + 1e-5f);
        }
        __syncthreads();
    }
    int gid = blockIdx.x * 256 + t;
    int r = gid >> 2, q = gid & 3;
    if (r >= NN) return;
    float acc[16];
    #pragma unroll
    for (int c = 0; c < 16; c++) acc[c] = 0.f;
    const float4* x4 = (const float4*)(X + (size_t)r * 64);
    const float* wq = Wg + q * 16;
    for (int kq = 0; kq < 16; kq++) {
        float4 xv = x4[kq];
        float xs[4] = {xv.x, xv.y, xv.z, xv.w};
        #pragma unroll
        for (int j = 0; j < 4; j++) {
            int k = kq * 4 + j;
            float v = xs[j];
            if (BN) {
                v = (v - mus[k]) * invs[k];
                v = v > 0.f ? v : 0.f;
            }
            const float4* w4 = (const float4*)(wq + k * 64);
            float4 w0 = w4[0], w1 = w4[1], w2 = w4[2], w3 = w4[3];
            acc[0]  = fmaf(v, w0.x, acc[0]);  acc[1]  = fmaf(v, w0.y, acc[1]);
            acc[2]  = fmaf(v, w0.z, acc[2]);  acc[3]  = fmaf(v, w0.w, acc[3]);
            acc[4]  = fmaf(v, w1.x, acc[4]);  acc[5]  = fmaf(v, w1.y, acc[5]);
            acc[6]  = fmaf(v, w1.z, acc[6]);  acc[7]  = fmaf(v, w1.w, acc[7]);
            acc[8]  = fmaf(v, w2.x, acc[8]);  acc[9]  = fmaf(v, w2.y, acc[9]);
            acc[10] = fmaf(v, w2.z, acc[10]); acc[11] = fmaf(v, w2.w, acc[11]);
            acc[12] = fmaf(v, w3.x, acc[12]); acc[13] = fmaf(v, w3.y, acc[13]);
            acc[14] = fmaf(v, w3.z, acc[14]); acc[15] = fmaf(v, w3.w, acc[15]);
        }
    }
    float4* o4 = (float4*)(H + (size_t)r * 64 + q * 16);
    #pragma unroll
    for (int u = 0; u < 4; u++) {
        float4 o;
        o.x = acc[4 * u]; o.y = acc[4 * u + 1]; o.z = acc[4 * u + 2]; o.w = acc[4 * u + 3];
        o4[u] = o;
    }
}

// ---------------- aggregation: 16 lanes/node, 4 nodes/wave, float4 gathers ----------------
// MODE 0: outv = v                          (odd cj, mid-block)
// MODE 1: outv = v; S = v                   (cj == 0)
// MODE 2: v2 = v + S; outv = v2; S += v2    (end of block, cj = 2,4,6,8,10)
// MODE 3: MODE 2 + relu + pooled atomicMax  (cj == 12, final conv)
// STATS: accumulate sum/sumsq of the written value into bnpart (for next conv's BN)

template <int MODE, int STATS>
__global__ __launch_bounds__(256) void aggregate_k(const float* __restrict__ H, const int* __restrict__ row_start,
                                                   const int* __restrict__ csr_src, const float* __restrict__ w,
                                                   const float* __restrict__ dis, const float* __restrict__ bias,
                                                   float* __restrict__ outv, float* __restrict__ S,
                                                   const int* __restrict__ batch, float* __restrict__ pooled,
                                                   float* __restrict__ bnpart) {
    int t = threadIdx.x;
    int wvid = t >> 6;           // wave 0..3
    int lane = t & 63;
    int g = lane >> 4;           // node-group within wave 0..3
    int li = lane & 15;          // lane within group (features 4*li..4*li+3)
    int node = blockIdx.x * 16 + wvid * 4 + g;
    int s0 = row_start[node], s1 = row_start[node + 1];
    float4 acc = {0.f, 0.f, 0.f, 0.f};
    int k = s0;
    for (; k + 4 <= s1; k += 4) {
        int i0 = csr_src[k], i1 = csr_src[k + 1], i2 = csr_src[k + 2], i3 = csr_src[k + 3];
        float w0 = w[k] * dis[i0];
        float w1 = w[k + 1] * dis[i1];
        float w2 = w[k + 2] * dis[i2];
        float w3 = w[k + 3] * dis[i3];
        float4 h0 = *(const float4*)(H + (size_t)i0 * 64 + li * 4);
        float4 h1 = *(const float4*)(H + (size_t)i1 * 64 + li * 4);
        float4 h2 = *(const float4*)(H + (size_t)i2 * 64 + li * 4);
        float4 h3 = *(const float4*)(H + (size_t)i3 * 64 + li * 4);
        acc.x = fmaf(h0.x, w0, acc.x); acc.y = fmaf(h0.y, w0, acc.y);
        acc.z = fmaf(h0.z, w0, acc.z); acc.w = fmaf(h0.w, w0, acc.w);
        acc.x = fmaf(h1.x, w1, acc.x); acc.y = fmaf(h1.y, w1, acc.y);
        acc.z = fmaf(h1.z, w1, acc.z); acc.w = fmaf(h1.w, w1, acc.w);
        acc.x = fmaf(h2.x, w2, acc.x); acc.y = fmaf(h2.y, w2, acc.y);
        acc.z = fmaf(h2.z, w2, acc.z); acc.w = fmaf(h2.w, w2, acc.w);
        acc.x = fmaf(h3.x, w3, acc.x); acc.y = fmaf(h3.y, w3, acc.y);
        acc.z = fmaf(h3.z, w3, acc.z); acc.w = fmaf(h3.w, w3, acc.w);
    }
    for (; k + 2 <= s1; k += 2) {
        int ia = csr_src[k], ib = csr_src[k + 1];
        float wa = w[k] * dis[ia];
        float wb = w[k + 1] * dis[ib];
        float4 ha = *(const float4*)(H + (size_t)ia * 64 + li * 4);
        float4 hb = *(const float4*)(H + (size_t)ib * 64 + li * 4);
        acc.x = fmaf(ha.x, wa, acc.x); acc.y = fmaf(ha.y, wa, acc.y);
        acc.z = fmaf(ha.z, wa, acc.z); acc.w = fmaf(ha.w, wa, acc.w);
        acc.x = fmaf(hb.x, wb, acc.x); acc.y = fmaf(hb.y, wb, acc.y);
        acc.z = fmaf(hb.z, wb, acc.z); acc.w = fmaf(hb.w, wb, acc.w);
    }
    if (k < s1) {
        int ia = csr_src[k];
        float wa = w[k] * dis[ia];
        float4 ha = *(const float4*)(H + (size_t)ia * 64 + li * 4);
        acc.x = fmaf(ha.x, wa, acc.x); acc.y = fmaf(ha.y, wa, acc.y);
        acc.z = fmaf(ha.z, wa, acc.z); acc.w = fmaf(ha.w, wa, acc.w);
    }
    float dn = dis[node];
    float dnn = dn * dn;
    float4 hs = *(const float4*)(H + (size_t)node * 64 + li * 4);
    float4 b4 = *(const float4*)(bias + li * 4);
    float4 v;
    v.x = fmaf(acc.x, dn, fmaf(hs.x, dnn, b4.x));
    v.y = fmaf(acc.y, dn, fmaf(hs.y, dnn, b4.y));
    v.z = fmaf(acc.z, dn, fmaf(hs.z, dnn, b4.z));
    v.w = fmaf(acc.w, dn, fmaf(hs.w, dnn, b4.w));
    size_t oi = (size_t)node * 64 + li * 4;
    float4 sv;  // the value actually written to outv (BN input for next conv)
    if (MODE == 0) {
        *(float4*)(outv + oi) = v;
        sv = v;
    } else if (MODE == 1) {
        *(float4*)(outv + oi) = v;
        *(float4*)(S + oi) = v;
        sv = v;
    } else {
        float4 s = *(const float4*)(S + oi);
        float4 v2;
        v2.x = v.x + s.x; v2.y = v.y + s.y; v2.z = v.z + s.z; v2.w = v.w + s.w;
        *(float4*)(outv + oi) = v2;
        float4 s2;
        s2.x = s.x + v2.x; s2.y = s.y + v2.y; s2.z = s.z + v2.z; s2.w = s.w + v2.w;
        *(float4*)(S + oi) = s2;
        sv = v2;
        if (MODE == 3) {
            float* pb = pooled + (size_t)batch[node] * 64 + li * 4;
            float r0 = v2.x > 0.f ? v2.x : 0.f;
            float r1 = v2.y > 0.f ? v2.y : 0.f;
            float r2 = v2.z > 0.f ? v2.z : 0.f;
            float r3 = v2.w > 0.f ? v2.w : 0.f;
            atomicMax((int*)(pb + 0), __float_as_int(r0));
            atomicMax((int*)(pb + 1), __float_as_int(r1));
            atomicMax((int*)(pb + 2), __float_as_int(r2));
            atomicMax((int*)(pb + 3), __float_as_int(r3));
        }
    }
    if (STATS) {
        __shared__ float reds[16 * 65];
        __shared__ float redq[16 * 65];
        int gg = wvid * 4 + g;  // node index within block, 0..15
        int fb = li * 4;
        reds[gg * 65 + fb + 0] = sv.x; redq[gg * 65 + fb + 0] = sv.x * sv.x;
        reds[gg * 65 + fb + 1] = sv.y; redq[gg * 65 + fb + 1] = sv.y * sv.y;
        reds[gg * 65 + fb + 2] = sv.z; redq[gg * 65 + fb + 2] = sv.z * sv.z;
        reds[gg * 65 + fb + 3] = sv.w; redq[gg * 65 + fb + 3] = sv.w * sv.w;
        __syncthreads();
        if (t < 128) {
            int f = t & 63;
            const float* src = (t < 64) ? reds : redq;
            float s = 0.f;
            #pragma unroll
            for (int i = 0; i < 16; i++) s += src[i * 65 + f];
            int rep = blockIdx.x & (BNP_REPS - 1);
            atomicAdd(bnpart + rep * 128 + ((t < 64) ? 0 : 64) + f, s);
        }
    }
}

__global__ void final_k(const float* __restrict__ pooled, const float* __restrict__ linW,
                        const float* __restrict__ linb, float* __restrict__ outp) {
    int g = blockIdx.x, c = threadIdx.x;  // 64 threads
    float v = pooled[(size_t)g * 64 + c];
    float p0 = v * linW[c * 2 + 0];
    float p1 = v * linW[c * 2 + 1];
    #pragma unroll
    for (int off = 32; off > 0; off >>= 1) {
        p0 += __shfl_down(p0, off, 64);
        p1 += __shfl_down(p1, off, 64);
    }
    if (c == 0) {
        outp[g * 2 + 0] = p0 + linb[0];
        outp[g * 2 + 1] = p1 + linb[1];
    }
}

// ---------------- host ----------------

extern "C" void kernel_launch(void* const* d_in, const int* in_sizes, int n_in,
                              void* d_out, int out_size, void* d_ws, size_t ws_size,
                              hipStream_t stream) {
    const float* x        = (const float*)d_in[0];
    const int*   ei       = (const int*)d_in[1];
    const int*   srcp     = ei;
    const int*   dstp     = ei + NE;
    const int*   batch    = (const int*)d_in[2];
    const float* edge_attr= (const float*)d_in[4];
    const float* Wlin1    = (const float*)d_in[5];
    const float* bias1    = (const float*)d_in[6];
    const float* m1W1     = (const float*)d_in[7];
    const float* m1b1     = (const float*)d_in[8];
    const float* m2W1     = (const float*)d_in[9];
    const float* m2b1     = (const float*)d_in[10];
    const float* hWlin    = (const float*)d_in[11];
    const float* hbias    = (const float*)d_in[12];
    const float* hm1W     = (const float*)d_in[13];
    const float* hm1b     = (const float*)d_in[14];
    const float* hm2W     = (const float*)d_in[15];
    const float* hm2b     = (const float*)d_in[16];
    const float* linW     = (const float*)d_in[17];
    const float* linb     = (const float*)d_in[18];
    float* outp = (float*)d_out;

    char* ws = (char*)d_ws;
    size_t off = 0;
    auto alloc = [&](size_t bytes) -> char* {
        char* p = ws + off;
        off += (bytes + 255) & ~(size_t)255;
        return p;
    };
    int*   cursor   = (int*)alloc((size_t)NN * 4);
    int*   row_start= (int*)alloc((size_t)(NN + 1) * 4);
    int*   csr_src  = (int*)alloc((size_t)NE * 4);
    int*   csr_eid  = (int*)alloc((size_t)NE * 4);
    float* ewbuf    = (float*)alloc((size_t)NCONV * NE * 4);
    float* disbuf   = (float*)alloc((size_t)NCONV * NN * 4);
    float* hbuf     = (float*)alloc((size_t)NN * 64 * 4);
    float* curbuf   = (float*)alloc((size_t)NN * 64 * 4);
    float* Sbuf     = (float*)alloc((size_t)NN * 64 * 4);
    float* bnpart   = (float*)alloc((size_t)NBN * BNP_REPS * 128 * 4);
    float* pooled   = (float*)alloc((size_t)NG * 64 * 4);
    float* wbuf     = (float*)alloc((size_t)NCONV * WSTRIDE * 4);
    int*   bsum     = (int*)alloc((size_t)SCAN_B * 4);

    const int TB = 256;
    int gN   = (NN + TB - 1) / TB;            // 196
    int gE   = (NE + TB - 1) / TB;            // 3125
    int gA   = NN / 16;                       // 3125 (exact)
    int gG   = (NN * 4 + TB - 1) / TB;        // 782
    int gZ   = (NBN * BNP_REPS * 128) / TB;   // 384 (covers NN and NG*64 too)
    int gW   = (NCONV * 289 + TB - 1) / TB;

    // CSR build
    zero_init_k<<<gZ, TB, 0, stream>>>(cursor, pooled, bnpart);
    count_k<<<gE, TB, 0, stream>>>(dstp, cursor);
    scan_blocksum_k<<<SCAN_B, TB, 0, stream>>>(cursor, bsum);
    scan_bsum_k<<<1, TB, 0, stream>>>(bsum, row_start);
    scan_local_k<<<SCAN_B, TB, 0, stream>>>(cursor, bsum, row_start);
    scatter_k<<<gE, TB, 0, stream>>>(srcp, dstp, cursor, csr_src, csr_eid);

    // edge weights for all 13 convs (raw sigmoid; dis folded in at aggregate time)
    pack_weights_k<<<gW, TB, 0, stream>>>(m1W1, m1b1, m2W1, m2b1, hm1W, hm1b, hm2W, hm2b, wbuf);
    edge_mlp_k<<<gE, TB, 0, stream>>>(edge_attr, csr_eid, wbuf, ewbuf);
    deg_dis_k<<<dim3(gN, NCONV), TB, 0, stream>>>(row_start, ewbuf, disbuf);

    // conv 0 (no BN), then 12 hidden convs; BN stats flow through bnpart slabs
    for (int cj = 0; cj < NCONV; cj++) {
        const float* Win  = (cj == 0) ? Wlin1 : (hWlin + (size_t)(cj - 1) * 4096);
        const float* bin  = (cj == 0) ? bias1 : (hbias + (size_t)(cj - 1) * 64);
        const float* Xin  = (cj == 0) ? x : curbuf;
        if (cj > 0) {
            gemm_k<true><<<gG, TB, 0, stream>>>(Xin, Win, bnpart + (size_t)(cj - 1) * BNP_REPS * 128, hbuf);
        } else {
            gemm_k<false><<<gG, TB, 0, stream>>>(Xin, Win, nullptr, hbuf);
        }
        const float* wcc = ewbuf + (size_t)cj * NE;
        const float* dcc = disbuf + (size_t)cj * NN;
        float* bnp = (cj < NBN) ? (bnpart + (size_t)cj * BNP_REPS * 128) : nullptr;
        if (cj == 0)
            aggregate_k<1, 1><<<gA, TB, 0, stream>>>(hbuf, row_start, csr_src, wcc, dcc, bin, curbuf, Sbuf, batch, pooled, bnp);
        else if (cj == 12)
            aggregate_k<3, 0><<<gA, TB, 0, stream>>>(hbuf, row_start, csr_src, wcc, dcc, bin, curbuf, Sbuf, batch, pooled, bnp);
        else if ((cj & 1) == 0)
            aggregate_k<2, 1><<<gA, TB, 0, stream>>>(hbuf, row_start, csr_src, wcc, dcc, bin, curbuf, Sbuf, batch, pooled, bnp);
        else
            aggregate_k<0, 1><<<gA, TB, 0, stream>>>(hbuf, row_start, csr_src, wcc, dcc, bin, curbuf, Sbuf, batch, pooled, bnp);
    }

    // readout
    final_k<<<NG, 64, 0, stream>>>(pooled, linW, linb, outp);
}